// Round 7
// baseline (149.831 us; speedup 1.0000x reference)
//
#include <hip/hip_runtime.h>
#include <hip/hip_fp8.h>

#define VOCAB 100000
#define DIM 128
#define BATCH 65536
#define N_NEG 10

// 8 lanes/group, 2 elements/group, 8 groups/wave, 4 waves/block => 64 elems/block
#define BLOCKS (BATCH / 64)   // 1024
#define QSCALE 256.0f
#define QINV   (1.0f / 256.0f)

// quantize grid: 3125 quantize blocks + prefetch-only blocks that warm the LLC
// with the data the gather will read (u rows actually used, neg/pos indices).
#define QBLOCKS      3125
#define PF_U_BLOCKS  1024   // 262144 threads: elem=g>>2 (0..65535), q=g&3, 8 float4 each
#define PF_NEG_BLOCKS 160   // 40960 threads x 4 uint4 = 163840 uint4 = all of neg_v
#define PF_POS_BLOCKS  32   // 8192 threads x (2+2) uint4 = pos_u + pos_v
#define QTOTAL (QBLOCKS + PF_U_BLOCKS + PF_NEG_BLOCKS + PF_POS_BLOCKS)

typedef float v4f __attribute__((ext_vector_type(4)));
typedef int   v4i __attribute__((ext_vector_type(4)));
typedef int   v2i __attribute__((ext_vector_type(2)));
typedef float v2f __attribute__((ext_vector_type(2)));

// ---------- fp8 helpers ----------
// Round-2 lesson: no nontemporal loads (harness fills already evict LLC; nt made
// reused data bypass cache, +15us).
// Round-4/5/6 lesson: gather is bound by cold-miss service rate, not by
// outstanding-request count (MLP curve flat from ~15 loads/lane up).
#if __has_builtin(__builtin_amdgcn_cvt_pk_fp8_f32) && __has_builtin(__builtin_amdgcn_cvt_pk_f32_fp8)
__device__ __forceinline__ unsigned int pack4_fp8(float a, float b, float c, float d) {
    int r = __builtin_amdgcn_cvt_pk_fp8_f32(a, b, 0, false);   // bytes 0,1
    r = __builtin_amdgcn_cvt_pk_fp8_f32(c, d, r, true);        // bytes 2,3
    return (unsigned int)r;
}
#else
__device__ __forceinline__ unsigned int pack4_fp8(float a, float b, float c, float d) {
    unsigned int r =  (unsigned int)__hip_fp8_e4m3(a).__x;
    r |= (unsigned int)__hip_fp8_e4m3(b).__x << 8;
    r |= (unsigned int)__hip_fp8_e4m3(c).__x << 16;
    r |= (unsigned int)__hip_fp8_e4m3(d).__x << 24;
    return r;
}
#endif

#if __has_builtin(__builtin_amdgcn_cvt_pk_f32_fp8)
__device__ __forceinline__ void fma4_fp8(float& s, unsigned int x, const float* u) {
    v2f lo = __builtin_amdgcn_cvt_pk_f32_fp8(x, false);
    v2f hi = __builtin_amdgcn_cvt_pk_f32_fp8(x, true);
    s += u[0] * lo.x + u[1] * lo.y + u[2] * hi.x + u[3] * hi.y;
}
#else
__device__ __forceinline__ float fp8_to_f(unsigned int b) {
    __hip_fp8_e4m3 t; t.__x = (__hip_fp8_storage_t)b; return (float)t;
}
__device__ __forceinline__ void fma4_fp8(float& s, unsigned int x, const float* u) {
    s += u[0] * fp8_to_f(x & 0xffu) + u[1] * fp8_to_f((x >> 8) & 0xffu)
       + u[2] * fp8_to_f((x >> 16) & 0xffu) + u[3] * fp8_to_f(x >> 24);
}
#endif

__device__ __forceinline__ float dot16_fp8(uint4 w, const float* uf) {
    float s = 0.0f;
    fma4_fp8(s, w.x, uf + 0);
    fma4_fp8(s, w.y, uf + 4);
    fma4_fp8(s, w.z, uf + 8);
    fma4_fp8(s, w.w, uf + 12);
    return s;
}

// softplus(x)/ln2 = max(y,0) + log2(1+2^-|y|), y = x*log2e  (native exp2/log2)
__device__ __forceinline__ float softplus_log2(float x) {
    const float y = x * 1.44269504f;
    const float t = __builtin_amdgcn_exp2f(-fabsf(y));
    return fmaxf(y, 0.0f) + __builtin_amdgcn_logf(1.0f + t);
}

__global__ void zero_out_kernel(float* out) { out[0] = 0.0f; }

// ---------- quantize v-table + LLC prefetch of gather inputs ----------
// Blocks [0, QBLOCKS): quantize v_weight -> fp8 table (zero-out folded in).
// Blocks [QBLOCKS, QTOTAL): touch-only loads of the u rows the gather will use
// (indices from pos_u) plus neg_v / pos_u / pos_v, so the gather's reads become
// LLC hits instead of ~900-cycle HBM misses. Values kept alive via asm sink
// (no stores, no numerics impact). In-iteration LLC footprint ~100MB < 256MB.
__global__ __launch_bounds__(256) void quantize_v_kernel(
    const float4* __restrict__ in, uint4* __restrict__ out, float* __restrict__ loss_out,
    const int* __restrict__ pos_u, const int* __restrict__ pos_v,
    const int* __restrict__ neg_v, const float4* __restrict__ u_weight)
{
    const int bid = blockIdx.x;
    const int tid = threadIdx.x;

    if (bid < QBLOCKS) {
        const int i = bid * 256 + tid;   // one 16-float group
        if (i == 0) loss_out[0] = 0.0f;
        const float4 a = in[i * 4 + 0];
        const float4 b = in[i * 4 + 1];
        const float4 c = in[i * 4 + 2];
        const float4 d = in[i * 4 + 3];
        uint4 r;
        r.x = pack4_fp8(a.x * QSCALE, a.y * QSCALE, a.z * QSCALE, a.w * QSCALE);
        r.y = pack4_fp8(b.x * QSCALE, b.y * QSCALE, b.z * QSCALE, b.w * QSCALE);
        r.z = pack4_fp8(c.x * QSCALE, c.y * QSCALE, c.z * QSCALE, c.w * QSCALE);
        r.w = pack4_fp8(d.x * QSCALE, d.y * QSCALE, d.z * QSCALE, d.w * QSCALE);
        out[i] = r;
        return;
    }

    if (bid < QBLOCKS + PF_U_BLOCKS) {
        // warm the u rows the gather will read: 65536 elems x 4 quarter-rows
        const int g = (bid - QBLOCKS) * 256 + tid;     // 0..262143
        const int elem = g >> 2;
        const int q    = g & 3;
        const float4* __restrict__ p = u_weight + (size_t)pos_u[elem] * 32 + q * 8;
        float acc = p[0].x + p[1].x + p[2].x + p[3].x
                  + p[4].x + p[5].x + p[6].x + p[7].x;
        asm volatile("" :: "v"(acc));
        return;
    }

    if (bid < QBLOCKS + PF_U_BLOCKS + PF_NEG_BLOCKS) {
        // warm neg_v: 163840 uint4 total
        const int g = (bid - QBLOCKS - PF_U_BLOCKS) * 256 + tid;   // 0..40959
        const uint4* __restrict__ p = (const uint4*)neg_v + (size_t)g * 4;
        const uint4 a = p[0], b = p[1], c = p[2], d = p[3];
        unsigned int acc = a.x + b.x + c.x + d.x;
        asm volatile("" :: "v"(acc));
        return;
    }

    {
        // warm pos_u + pos_v: 16384 uint4 each
        const int g = (bid - QBLOCKS - PF_U_BLOCKS - PF_NEG_BLOCKS) * 256 + tid; // 0..8191
        const uint4* __restrict__ a = (const uint4*)pos_u + (size_t)g * 2;
        const uint4* __restrict__ b = (const uint4*)pos_v + (size_t)g * 2;
        const uint4 x0 = a[0], x1 = a[1], y0 = b[0], y1 = b[1];
        unsigned int acc = x0.x + x1.x + y0.x + y1.x;
        asm volatile("" :: "v"(acc));
    }
}

// ---------- gather: 2 elements per 8-lane group, FULL register batch ----------
__global__ __launch_bounds__(256, 3) void skipgram_loss_fp8_kernel(
    const int* __restrict__ pos_u,
    const int* __restrict__ pos_v,
    const int* __restrict__ neg_v,
    const float4* __restrict__ u_weight,   // VOCAB x 32 float4 (fp32)
    const uint4* __restrict__ v8,          // VOCAB x 8 uint4 (fp8, 128 B/row)
    float* __restrict__ out)
{
    const int tid  = threadIdx.x;
    const int lane = tid & 63;
    const int wave = tid >> 6;
    const int sub  = lane & 7;       // 16 B slice within the 128-B fp8 row
    const int grp  = lane >> 3;

    const int gg = (blockIdx.x * 4 + wave) * 8 + grp;  // global group id
    const int b0 = gg * 2;                              // even

    // ---- vectorized index loads ----
    const v2i pu = *(const v2i*)(pos_u + b0);
    const v2i pv = *(const v2i*)(pos_v + b0);
    const v4i* __restrict__ np = (const v4i*)(neg_v + (size_t)b0 * N_NEG);  // 80B, 16B-aligned
    const v4i q0 = np[0];
    const v4i q1 = np[1];
    const v4i q2 = np[2];
    const v4i q3 = np[3];
    const v4i q4 = np[4];

    // slot 0 = positive, slots 1..10 = negatives
    const int i0[N_NEG + 1] = { pv.x, q0.x, q0.y, q0.z, q0.w, q1.x, q1.y, q1.z, q1.w, q2.x, q2.y };
    const int i1[N_NEG + 1] = { pv.y, q2.z, q2.w, q3.x, q3.y, q3.z, q3.w, q4.x, q4.y, q4.z, q4.w };

    // ---- PHASE 1: issue ALL data loads (22 v8 gathers + 8 u-row loads) ----
    uint4 w0[N_NEG + 1], w1[N_NEG + 1];
    #pragma unroll
    for (int j = 0; j <= N_NEG; ++j) {
        w0[j] = v8[(size_t)i0[j] * 8 + sub];
        w1[j] = v8[(size_t)i1[j] * 8 + sub];
    }
    const float4* __restrict__ urow0 = u_weight + (size_t)pu.x * 32 + sub * 4;
    const float4* __restrict__ urow1 = u_weight + (size_t)pu.y * 32 + sub * 4;
    const float4 t00 = urow0[0];
    const float4 t01 = urow0[1];
    const float4 t02 = urow0[2];
    const float4 t03 = urow0[3];
    const float4 t10 = urow1[0];
    const float4 t11 = urow1[1];
    const float4 t12 = urow1[2];
    const float4 t13 = urow1[3];

    // ---- PHASE 2: consume ----
    float uf0[16], uf1[16];
    uf0[0]  = t00.x; uf0[1]  = t00.y; uf0[2]  = t00.z; uf0[3]  = t00.w;
    uf0[4]  = t01.x; uf0[5]  = t01.y; uf0[6]  = t01.z; uf0[7]  = t01.w;
    uf0[8]  = t02.x; uf0[9]  = t02.y; uf0[10] = t02.z; uf0[11] = t02.w;
    uf0[12] = t03.x; uf0[13] = t03.y; uf0[14] = t03.z; uf0[15] = t03.w;
    uf1[0]  = t10.x; uf1[1]  = t10.y; uf1[2]  = t10.z; uf1[3]  = t10.w;
    uf1[4]  = t11.x; uf1[5]  = t11.y; uf1[6]  = t11.z; uf1[7]  = t11.w;
    uf1[8]  = t12.x; uf1[9]  = t12.y; uf1[10] = t12.z; uf1[11] = t12.w;
    uf1[12] = t13.x; uf1[13] = t13.y; uf1[14] = t13.z; uf1[15] = t13.w;

    float a0[N_NEG + 1], a1[N_NEG + 1];
    #pragma unroll
    for (int j = 0; j <= N_NEG; ++j) {
        a0[j] = dot16_fp8(w0[j], uf0);
        a1[j] = dot16_fp8(w1[j], uf1);
    }

    #pragma unroll
    for (int m = 1; m < 8; m <<= 1) {
        #pragma unroll
        for (int j = 0; j <= N_NEG; ++j) {
            a0[j] += __shfl_xor(a0[j], m, 64);
            a1[j] += __shfl_xor(a1[j], m, 64);
        }
    }

    float s0 = fminf(fmaxf(a0[0] * QINV, -10.0f), 10.0f);
    float s1 = fminf(fmaxf(a1[0] * QINV, -10.0f), 10.0f);
    float loss2 = softplus_log2(-s0) + softplus_log2(-s1);
    #pragma unroll
    for (int n = 0; n < N_NEG; ++n)
        loss2 -= softplus_log2(a0[n + 1] * QINV) + softplus_log2(a1[n + 1] * QINV);
    float loss = loss2 * 0.69314718f;   // loss(b0) + loss(b1), uniform in group

    // Butterfly over masks 8,16,32 sums the 8 distinct group values once each.
    #pragma unroll
    for (int m = 8; m < 64; m <<= 1) loss += __shfl_xor(loss, m, 64);

    __shared__ float smem[4];
    if (lane == 0) smem[wave] = loss;
    __syncthreads();
    if (tid == 0)
        atomicAdd(out, (smem[0] + smem[1] + smem[2] + smem[3]) * (1.0f / (float)BATCH));
}

// ---------- fp32 fallback if ws is too small ----------
__device__ __forceinline__ float dot4(float4 a, float4 b) {
    return a.x * b.x + a.y * b.y + a.z * b.z + a.w * b.w;
}

__global__ __launch_bounds__(256) void skipgram_loss_fp32_kernel(
    const int* __restrict__ pos_u,
    const int* __restrict__ pos_v,
    const int* __restrict__ neg_v,
    const float4* __restrict__ u_weight,
    const float4* __restrict__ v_weight,
    float* __restrict__ out)
{
    const int tid  = threadIdx.x;
    const int lane = tid & 63;
    const int wave = tid >> 6;
    const int sub  = lane & 7;
    const int grp  = lane >> 3;

    const int b = ((blockIdx.x * 4 + wave) * 8 + grp);

    const int iu = pos_u[b];
    const int iv = pos_v[b];

    const float4* __restrict__ urow = u_weight + iu * 32;
    float4 u0 = urow[0 * 8 + sub];
    float4 u1 = urow[1 * 8 + sub];
    float4 u2 = urow[2 * 8 + sub];
    float4 u3 = urow[3 * 8 + sub];

    const float4* __restrict__ vrow = v_weight + iv * 32;
    float p = dot4(u0, vrow[0 * 8 + sub]) + dot4(u1, vrow[1 * 8 + sub])
            + dot4(u2, vrow[2 * 8 + sub]) + dot4(u3, vrow[3 * 8 + sub]);

    float nd[N_NEG];
    #pragma unroll
    for (int n = 0; n < N_NEG; ++n) {
        const int idx = neg_v[b * N_NEG + n];
        const float4* __restrict__ wrow = v_weight + idx * 32;
        nd[n] = dot4(u0, wrow[0 * 8 + sub]) + dot4(u1, wrow[1 * 8 + sub])
              + dot4(u2, wrow[2 * 8 + sub]) + dot4(u3, wrow[3 * 8 + sub]);
    }

    #pragma unroll
    for (int m = 1; m < 8; m <<= 1) {
        p += __shfl_xor(p, m, 64);
        #pragma unroll
        for (int n = 0; n < N_NEG; ++n) nd[n] += __shfl_xor(nd[n], m, 64);
    }

    float s = fminf(fmaxf(p, -10.0f), 10.0f);
    float loss2 = softplus_log2(-s);
    #pragma unroll
    for (int n = 0; n < N_NEG; ++n) loss2 -= softplus_log2(nd[n]);
    float loss = loss2 * 0.69314718f;

    #pragma unroll
    for (int m = 8; m < 64; m <<= 1) loss += __shfl_xor(loss, m, 64);

    __shared__ float smem[4];
    if (lane == 0) smem[wave] = loss;
    __syncthreads();
    if (tid == 0)
        atomicAdd(out, (smem[0] + smem[1] + smem[2] + smem[3]) * (1.0f / (float)BATCH));
}

extern "C" void kernel_launch(void* const* d_in, const int* in_sizes, int n_in,
                              void* d_out, int out_size, void* d_ws, size_t ws_size,
                              hipStream_t stream) {
    const int*    pos_u    = (const int*)d_in[0];
    const int*    pos_v    = (const int*)d_in[1];
    const int*    neg_v    = (const int*)d_in[2];
    const float4* u_weight = (const float4*)d_in[3];
    const float4* v_weight = (const float4*)d_in[4];
    float* out = (float*)d_out;

    const size_t table_bytes = (size_t)VOCAB * DIM;        // 12.8 MB fp8
    if (ws_size >= table_bytes) {
        uint4* v8 = (uint4*)d_ws;
        quantize_v_kernel<<<QTOTAL, 256, 0, stream>>>(
            v_weight, v8, out, pos_u, pos_v, neg_v, u_weight);
        skipgram_loss_fp8_kernel<<<BLOCKS, 256, 0, stream>>>(
            pos_u, pos_v, neg_v, u_weight, v8, out);
    } else {
        zero_out_kernel<<<1, 1, 0, stream>>>(out);
        skipgram_loss_fp32_kernel<<<BATCH / 32, 256, 0, stream>>>(
            pos_u, pos_v, neg_v, u_weight, v_weight, out);
    }
}

// Round 8
// 140.329 us; speedup vs baseline: 1.0677x; 1.0677x over previous
//
#include <hip/hip_runtime.h>
#include <hip/hip_fp8.h>

#define VOCAB 100000
#define DIM 128
#define BATCH 65536
#define N_NEG 10

// 8 lanes/group, 2 elements/group, 8 groups/wave, 4 waves/block => 64 elems/block
#define BLOCKS (BATCH / 64)   // 1024
#define QSCALE 256.0f
#define QINV   (1.0f / 256.0f)

typedef float v4f __attribute__((ext_vector_type(4)));
typedef int   v4i __attribute__((ext_vector_type(4)));
typedef int   v2i __attribute__((ext_vector_type(2)));
typedef float v2f __attribute__((ext_vector_type(2)));

// ---------- fp8 helpers ----------
// Experiment ledger (rounds 2-7):
//  - nontemporal loads: +15us (fills evict LLC anyway; nt made reused data bypass cache)
//  - occupancy-up / VGPR-squeeze (256,8): +17us (killed per-lane MLP)
//  - MLP beyond ~15 loads/lane: flat (bound by cold-miss service rate)
//  - LLC prefetch blocks in quantize: +10us (prefetch itself latency-bound, serialized)
// Best structure: 2 elems/group, full register batch, bounds(256,3), u-loads first.
#if __has_builtin(__builtin_amdgcn_cvt_pk_fp8_f32) && __has_builtin(__builtin_amdgcn_cvt_pk_f32_fp8)
__device__ __forceinline__ unsigned int pack4_fp8(float a, float b, float c, float d) {
    int r = __builtin_amdgcn_cvt_pk_fp8_f32(a, b, 0, false);   // bytes 0,1
    r = __builtin_amdgcn_cvt_pk_fp8_f32(c, d, r, true);        // bytes 2,3
    return (unsigned int)r;
}
#else
__device__ __forceinline__ unsigned int pack4_fp8(float a, float b, float c, float d) {
    unsigned int r =  (unsigned int)__hip_fp8_e4m3(a).__x;
    r |= (unsigned int)__hip_fp8_e4m3(b).__x << 8;
    r |= (unsigned int)__hip_fp8_e4m3(c).__x << 16;
    r |= (unsigned int)__hip_fp8_e4m3(d).__x << 24;
    return r;
}
#endif

#if __has_builtin(__builtin_amdgcn_cvt_pk_f32_fp8)
__device__ __forceinline__ void fma4_fp8(float& s, unsigned int x, const float* u) {
    v2f lo = __builtin_amdgcn_cvt_pk_f32_fp8(x, false);
    v2f hi = __builtin_amdgcn_cvt_pk_f32_fp8(x, true);
    s += u[0] * lo.x + u[1] * lo.y + u[2] * hi.x + u[3] * hi.y;
}
#else
__device__ __forceinline__ float fp8_to_f(unsigned int b) {
    __hip_fp8_e4m3 t; t.__x = (__hip_fp8_storage_t)b; return (float)t;
}
__device__ __forceinline__ void fma4_fp8(float& s, unsigned int x, const float* u) {
    s += u[0] * fp8_to_f(x & 0xffu) + u[1] * fp8_to_f((x >> 8) & 0xffu)
       + u[2] * fp8_to_f((x >> 16) & 0xffu) + u[3] * fp8_to_f(x >> 24);
}
#endif

__device__ __forceinline__ float dot16_fp8(uint4 w, const float* uf) {
    float s = 0.0f;
    fma4_fp8(s, w.x, uf + 0);
    fma4_fp8(s, w.y, uf + 4);
    fma4_fp8(s, w.z, uf + 8);
    fma4_fp8(s, w.w, uf + 12);
    return s;
}

// softplus(x)/ln2 = max(y,0) + log2(1+2^-|y|), y = x*log2e  (native exp2/log2)
__device__ __forceinline__ float softplus_log2(float x) {
    const float y = x * 1.44269504f;
    const float t = __builtin_amdgcn_exp2f(-fabsf(y));
    return fmaxf(y, 0.0f) + __builtin_amdgcn_logf(1.0f + t);
}

__global__ void zero_out_kernel(float* out) { out[0] = 0.0f; }

// ---------- quantize v-table (zero-out folded in) ----------
__global__ __launch_bounds__(256) void quantize_v_kernel(
    const float4* __restrict__ in, uint4* __restrict__ out, float* __restrict__ loss_out) {
    const int i = blockIdx.x * 256 + threadIdx.x;   // one 16-float group
    if (i == 0) loss_out[0] = 0.0f;
    const float4 a = in[i * 4 + 0];
    const float4 b = in[i * 4 + 1];
    const float4 c = in[i * 4 + 2];
    const float4 d = in[i * 4 + 3];
    uint4 r;
    r.x = pack4_fp8(a.x * QSCALE, a.y * QSCALE, a.z * QSCALE, a.w * QSCALE);
    r.y = pack4_fp8(b.x * QSCALE, b.y * QSCALE, b.z * QSCALE, b.w * QSCALE);
    r.z = pack4_fp8(c.x * QSCALE, c.y * QSCALE, c.z * QSCALE, c.w * QSCALE);
    r.w = pack4_fp8(d.x * QSCALE, d.y * QSCALE, d.z * QSCALE, d.w * QSCALE);
    out[i] = r;
}

// ---------- gather: 2 elements per 8-lane group, FULL register batch ----------
// u-row loads issued FIRST (cold HBM ~900cy) before the v8 gathers (LLC-warm,
// just written by quantize) so the longest-latency misses start earliest.
__global__ __launch_bounds__(256, 3) void skipgram_loss_fp8_kernel(
    const int* __restrict__ pos_u,
    const int* __restrict__ pos_v,
    const int* __restrict__ neg_v,
    const float4* __restrict__ u_weight,   // VOCAB x 32 float4 (fp32)
    const uint4* __restrict__ v8,          // VOCAB x 8 uint4 (fp8, 128 B/row)
    float* __restrict__ out)
{
    const int tid  = threadIdx.x;
    const int lane = tid & 63;
    const int wave = tid >> 6;
    const int sub  = lane & 7;       // 16 B slice within the 128-B fp8 row
    const int grp  = lane >> 3;

    const int gg = (blockIdx.x * 4 + wave) * 8 + grp;  // global group id
    const int b0 = gg * 2;                              // even

    // ---- vectorized index loads ----
    const v2i pu = *(const v2i*)(pos_u + b0);
    const v2i pv = *(const v2i*)(pos_v + b0);
    const v4i* __restrict__ np = (const v4i*)(neg_v + (size_t)b0 * N_NEG);  // 80B, 16B-aligned
    const v4i q0 = np[0];
    const v4i q1 = np[1];
    const v4i q2 = np[2];
    const v4i q3 = np[3];
    const v4i q4 = np[4];

    // ---- PHASE 1a: issue u-row loads first (cold HBM) ----
    const float4* __restrict__ urow0 = u_weight + (size_t)pu.x * 32 + sub * 4;
    const float4* __restrict__ urow1 = u_weight + (size_t)pu.y * 32 + sub * 4;
    const float4 t00 = urow0[0];
    const float4 t01 = urow0[1];
    const float4 t02 = urow0[2];
    const float4 t03 = urow0[3];
    const float4 t10 = urow1[0];
    const float4 t11 = urow1[1];
    const float4 t12 = urow1[2];
    const float4 t13 = urow1[3];

    // slot 0 = positive, slots 1..10 = negatives
    const int i0[N_NEG + 1] = { pv.x, q0.x, q0.y, q0.z, q0.w, q1.x, q1.y, q1.z, q1.w, q2.x, q2.y };
    const int i1[N_NEG + 1] = { pv.y, q2.z, q2.w, q3.x, q3.y, q3.z, q3.w, q4.x, q4.y, q4.z, q4.w };

    // ---- PHASE 1b: issue all 22 v8 gathers (LLC-warm) ----
    uint4 w0[N_NEG + 1], w1[N_NEG + 1];
    #pragma unroll
    for (int j = 0; j <= N_NEG; ++j) {
        w0[j] = v8[(size_t)i0[j] * 8 + sub];
        w1[j] = v8[(size_t)i1[j] * 8 + sub];
    }

    // ---- PHASE 2: consume ----
    float uf0[16], uf1[16];
    uf0[0]  = t00.x; uf0[1]  = t00.y; uf0[2]  = t00.z; uf0[3]  = t00.w;
    uf0[4]  = t01.x; uf0[5]  = t01.y; uf0[6]  = t01.z; uf0[7]  = t01.w;
    uf0[8]  = t02.x; uf0[9]  = t02.y; uf0[10] = t02.z; uf0[11] = t02.w;
    uf0[12] = t03.x; uf0[13] = t03.y; uf0[14] = t03.z; uf0[15] = t03.w;
    uf1[0]  = t10.x; uf1[1]  = t10.y; uf1[2]  = t10.z; uf1[3]  = t10.w;
    uf1[4]  = t11.x; uf1[5]  = t11.y; uf1[6]  = t11.z; uf1[7]  = t11.w;
    uf1[8]  = t12.x; uf1[9]  = t12.y; uf1[10] = t12.z; uf1[11] = t12.w;
    uf1[12] = t13.x; uf1[13] = t13.y; uf1[14] = t13.z; uf1[15] = t13.w;

    float a0[N_NEG + 1], a1[N_NEG + 1];
    #pragma unroll
    for (int j = 0; j <= N_NEG; ++j) {
        a0[j] = dot16_fp8(w0[j], uf0);
        a1[j] = dot16_fp8(w1[j], uf1);
    }

    #pragma unroll
    for (int m = 1; m < 8; m <<= 1) {
        #pragma unroll
        for (int j = 0; j <= N_NEG; ++j) {
            a0[j] += __shfl_xor(a0[j], m, 64);
            a1[j] += __shfl_xor(a1[j], m, 64);
        }
    }

    float s0 = fminf(fmaxf(a0[0] * QINV, -10.0f), 10.0f);
    float s1 = fminf(fmaxf(a1[0] * QINV, -10.0f), 10.0f);
    float loss2 = softplus_log2(-s0) + softplus_log2(-s1);
    #pragma unroll
    for (int n = 0; n < N_NEG; ++n)
        loss2 -= softplus_log2(a0[n + 1] * QINV) + softplus_log2(a1[n + 1] * QINV);
    float loss = loss2 * 0.69314718f;   // loss(b0) + loss(b1), uniform in group

    // Butterfly over masks 8,16,32 sums the 8 distinct group values once each.
    #pragma unroll
    for (int m = 8; m < 64; m <<= 1) loss += __shfl_xor(loss, m, 64);

    __shared__ float smem[4];
    if (lane == 0) smem[wave] = loss;
    __syncthreads();
    if (tid == 0)
        atomicAdd(out, (smem[0] + smem[1] + smem[2] + smem[3]) * (1.0f / (float)BATCH));
}

// ---------- fp32 fallback if ws is too small ----------
__device__ __forceinline__ float dot4(float4 a, float4 b) {
    return a.x * b.x + a.y * b.y + a.z * b.z + a.w * b.w;
}

__global__ __launch_bounds__(256) void skipgram_loss_fp32_kernel(
    const int* __restrict__ pos_u,
    const int* __restrict__ pos_v,
    const int* __restrict__ neg_v,
    const float4* __restrict__ u_weight,
    const float4* __restrict__ v_weight,
    float* __restrict__ out)
{
    const int tid  = threadIdx.x;
    const int lane = tid & 63;
    const int wave = tid >> 6;
    const int sub  = lane & 7;
    const int grp  = lane >> 3;

    const int b = ((blockIdx.x * 4 + wave) * 8 + grp);

    const int iu = pos_u[b];
    const int iv = pos_v[b];

    const float4* __restrict__ urow = u_weight + iu * 32;
    float4 u0 = urow[0 * 8 + sub];
    float4 u1 = urow[1 * 8 + sub];
    float4 u2 = urow[2 * 8 + sub];
    float4 u3 = urow[3 * 8 + sub];

    const float4* __restrict__ vrow = v_weight + iv * 32;
    float p = dot4(u0, vrow[0 * 8 + sub]) + dot4(u1, vrow[1 * 8 + sub])
            + dot4(u2, vrow[2 * 8 + sub]) + dot4(u3, vrow[3 * 8 + sub]);

    float nd[N_NEG];
    #pragma unroll
    for (int n = 0; n < N_NEG; ++n) {
        const int idx = neg_v[b * N_NEG + n];
        const float4* __restrict__ wrow = v_weight + idx * 32;
        nd[n] = dot4(u0, wrow[0 * 8 + sub]) + dot4(u1, wrow[1 * 8 + sub])
              + dot4(u2, wrow[2 * 8 + sub]) + dot4(u3, wrow[3 * 8 + sub]);
    }

    #pragma unroll
    for (int m = 1; m < 8; m <<= 1) {
        p += __shfl_xor(p, m, 64);
        #pragma unroll
        for (int n = 0; n < N_NEG; ++n) nd[n] += __shfl_xor(nd[n], m, 64);
    }

    float s = fminf(fmaxf(p, -10.0f), 10.0f);
    float loss2 = softplus_log2(-s);
    #pragma unroll
    for (int n = 0; n < N_NEG; ++n) loss2 -= softplus_log2(nd[n]);
    float loss = loss2 * 0.69314718f;

    #pragma unroll
    for (int m = 8; m < 64; m <<= 1) loss += __shfl_xor(loss, m, 64);

    __shared__ float smem[4];
    if (lane == 0) smem[wave] = loss;
    __syncthreads();
    if (tid == 0)
        atomicAdd(out, (smem[0] + smem[1] + smem[2] + smem[3]) * (1.0f / (float)BATCH));
}

extern "C" void kernel_launch(void* const* d_in, const int* in_sizes, int n_in,
                              void* d_out, int out_size, void* d_ws, size_t ws_size,
                              hipStream_t stream) {
    const int*    pos_u    = (const int*)d_in[0];
    const int*    pos_v    = (const int*)d_in[1];
    const int*    neg_v    = (const int*)d_in[2];
    const float4* u_weight = (const float4*)d_in[3];
    const float4* v_weight = (const float4*)d_in[4];
    float* out = (float*)d_out;

    const size_t table_bytes = (size_t)VOCAB * DIM;        // 12.8 MB fp8
    if (ws_size >= table_bytes) {
        uint4* v8 = (uint4*)d_ws;
        const int qblocks = (VOCAB * DIM / 16) / 256;      // 3125
        quantize_v_kernel<<<qblocks, 256, 0, stream>>>(v_weight, v8, out);
        skipgram_loss_fp8_kernel<<<BLOCKS, 256, 0, stream>>>(
            pos_u, pos_v, neg_v, u_weight, v8, out);
    } else {
        zero_out_kernel<<<1, 1, 0, stream>>>(out);
        skipgram_loss_fp32_kernel<<<BATCH / 32, 256, 0, stream>>>(
            pos_u, pos_v, neg_v, u_weight, v_weight, out);
    }
}